// Round 1
// 1788.868 us; speedup vs baseline: 1.0289x; 1.0289x over previous
//
#include <hip/hip_runtime.h>
#include <cstdint>
#include <cstddef>

typedef __attribute__((ext_vector_type(8))) short s8v;   // 8 x bf16 (4 VGPRs)
typedef __attribute__((ext_vector_type(4))) float f4v;   // 4 x f32

constexpr int Lc = 8, Bc = 8, Sc = 2048, Dc = 1024, Hc = 16, Fc = 4096;

__device__ __forceinline__ unsigned short f2bf(float f) {
    unsigned int u = __float_as_uint(f);
    u = (u + 0x7FFFu + ((u >> 16) & 1u)) >> 16;   // RNE
    return (unsigned short)u;
}

// async global->LDS, 16B per lane; LDS dest is wave-uniform base + lane*16
__device__ __forceinline__ void gload_lds16(const unsigned short* g, unsigned short* l) {
    __builtin_amdgcn_global_load_lds(
        (__attribute__((address_space(1))) void*)g,
        (__attribute__((address_space(3))) void*)l,
        16, 0, 0);
}

// ---------- transpose + cast: fp32 [L][R][C] -> bf16 [L][C][R] ----------
__global__ __launch_bounds__(256) void transpose_cast(
    const float* __restrict__ in, unsigned short* __restrict__ out, int R, int C) {
    __shared__ float tile[32][33];
    int l = blockIdx.z;
    int r0 = blockIdx.y << 5, c0 = blockIdx.x << 5;
    const float* ip = in + (size_t)l * R * C;
    unsigned short* op = out + (size_t)l * R * C;
    int tx = threadIdx.x & 31, ty = threadIdx.x >> 5;   // 32 x 8
#pragma unroll
    for (int i = 0; i < 4; i++)
        tile[ty + i * 8][tx] = ip[(size_t)(r0 + ty + i * 8) * C + (c0 + tx)];
    __syncthreads();
#pragma unroll
    for (int i = 0; i < 4; i++)
        op[(size_t)(c0 + ty + i * 8) * R + (r0 + tx)] = f2bf(tile[tx][ty + i * 8]);
}

// ---------- layernorm: fp32 [B][S][D] -> bf16, per-batch routed params ----------
__global__ __launch_bounds__(256) void ln_kernel(
    const float* __restrict__ x, const float* __restrict__ sc, const float* __restrict__ bi,
    const int* __restrict__ idx, unsigned short* __restrict__ out) {
    int row = blockIdx.x;           // b*S + s
    int b = row >> 11;              // S = 2048
    int l = idx[b];
    const float* xr = x + (size_t)row * Dc;
    int t = threadIdx.x;            // 256 threads x 4 floats = 1024
    float4 xv = *(const float4*)(xr + t * 4);
    float s = xv.x + xv.y + xv.z + xv.w;
    float ss = xv.x * xv.x + xv.y * xv.y + xv.z * xv.z + xv.w * xv.w;
#pragma unroll
    for (int off = 32; off; off >>= 1) { s += __shfl_xor(s, off); ss += __shfl_xor(ss, off); }
    __shared__ float red[2][4];
    int w = t >> 6, lane = t & 63;
    if (lane == 0) { red[0][w] = s; red[1][w] = ss; }
    __syncthreads();
    float tot = red[0][0] + red[0][1] + red[0][2] + red[0][3];
    float tots = red[1][0] + red[1][1] + red[1][2] + red[1][3];
    float mean = tot * (1.0f / Dc);
    float var = tots * (1.0f / Dc) - mean * mean;
    float r = rsqrtf(var + 1e-5f);
    float4 s4 = *(const float4*)(sc + (size_t)l * Dc + t * 4);
    float4 b4 = *(const float4*)(bi + (size_t)l * Dc + t * 4);
    ushort4 o;
    o.x = f2bf((xv.x - mean) * r * s4.x + b4.x);
    o.y = f2bf((xv.y - mean) * r * s4.y + b4.y);
    o.z = f2bf((xv.z - mean) * r * s4.z + b4.z);
    o.w = f2bf((xv.w - mean) * r * s4.w + b4.w);
    *(ushort4*)(out + (size_t)row * Dc + t * 4) = o;
}

// ---------- MFMA GEMM: C[b] = A[b](MxK bf16) @ Wt[idx[b]]^T + bias, epilogues ----------
// Wt stored as [L][N][K] bf16 (pre-transposed).  EPI: 0=bf16 store, 1=gelu->bf16, 2=resid add->fp32
// m97 structure: 128x128 tile, BK=32, linear LDS, global_load_lds width-16 staging.
template <int EPI>
__global__ __launch_bounds__(256) void gemm_kernel(
    const unsigned short* __restrict__ A, const unsigned short* __restrict__ Wt,
    const float* __restrict__ bias, const int* __restrict__ idx,
    const float* __restrict__ resid, void* __restrict__ out, int M, int N, int K) {
    int b = blockIdx.z;
    int l = idx[b];
    int m0 = blockIdx.y << 7, n0 = blockIdx.x << 7;
    const unsigned short* Ab = A + (size_t)b * M * K;
    const unsigned short* Wl = Wt + (size_t)l * N * K;
    __shared__ alignas(16) unsigned short As[128][32];  // linear (gload_lds needs it)
    __shared__ alignas(16) unsigned short Bs[128][32];
    int tid = threadIdx.x, w = tid >> 6, lane = tid & 63, quad = lane >> 4, lr = lane & 15;
    int wm = (w >> 1) << 6, wn = (w & 1) << 6;   // wave -> 64x64 region
    f4v acc[4][4];
#pragma unroll
    for (int i = 0; i < 4; i++)
#pragma unroll
        for (int j = 0; j < 4; j++) acc[i][j] = 0.f;

    // staging: wave w owns rows [32w,32w+32) of both tiles; 1KB chunk = 16 rows.
    // lane -> (row = lane>>2, 16B slot = lane&3) matches linear LDS order.
    int chrow = 32 * w + (lane >> 2);
    int ks = (lane & 3) * 8;                    // ushort offset of this lane's 16B
    const unsigned short* agp0 = Ab + (size_t)(m0 + chrow) * K + ks;
    const unsigned short* agp1 = agp0 + (size_t)16 * K;
    const unsigned short* bgp0 = Wl + (size_t)(n0 + chrow) * K + ks;
    const unsigned short* bgp1 = bgp0 + (size_t)16 * K;
    unsigned short* lA0 = &As[32 * w][0];
    unsigned short* lA1 = &As[32 * w + 16][0];
    unsigned short* lB0 = &Bs[32 * w][0];
    unsigned short* lB1 = &Bs[32 * w + 16][0];

    for (int k0 = 0; k0 < K; k0 += 32) {
        gload_lds16(agp0, lA0);
        gload_lds16(agp1, lA1);
        gload_lds16(bgp0, lB0);
        gload_lds16(bgp1, lB1);
        agp0 += 32; agp1 += 32; bgp0 += 32; bgp1 += 32;
        __syncthreads();                       // vmcnt drained -> tiles visible
        s8v af[4], bf[4];
#pragma unroll
        for (int i = 0; i < 4; i++) af[i] = *(const s8v*)&As[wm + i * 16 + lr][quad * 8];
#pragma unroll
        for (int j = 0; j < 4; j++) bf[j] = *(const s8v*)&Bs[wn + j * 16 + lr][quad * 8];
#pragma unroll
        for (int i = 0; i < 4; i++)
#pragma unroll
            for (int j = 0; j < 4; j++)
                acc[i][j] = __builtin_amdgcn_mfma_f32_16x16x32_bf16(af[i], bf[j], acc[i][j], 0, 0, 0);
        __syncthreads();                       // reads done before next stage
    }

    float bj[4];
#pragma unroll
    for (int j = 0; j < 4; j++) bj[j] = bias[(size_t)l * N + (n0 + wn + j * 16 + lr)];
    size_t obase = (size_t)b * M * N;
#pragma unroll
    for (int i = 0; i < 4; i++) {
#pragma unroll
        for (int r = 0; r < 4; r++) {
            int gm = m0 + wm + i * 16 + quad * 4 + r;   // C/D: row = quad*4+reg
            size_t rowoff = obase + (size_t)gm * N;
#pragma unroll
            for (int j = 0; j < 4; j++) {
                int gn = n0 + wn + j * 16 + lr;         // C/D: col = lane&15
                float val = acc[i][j][r] + bj[j];
                if constexpr (EPI == 0) {
                    ((unsigned short*)out)[rowoff + gn] = f2bf(val);
                } else if constexpr (EPI == 1) {
                    float g = 0.5f * val * (1.0f + tanhf(0.7978845608f * (val + 0.044715f * val * val * val)));
                    ((unsigned short*)out)[rowoff + gn] = f2bf(g);
                } else {
                    ((float*)out)[rowoff + gn] = resid[rowoff + gn] + val;
                }
            }
        }
    }
}

// ---------- flash attention: block = (q-tile 64, head, batch), kv chunks of 64 ----------
__global__ __launch_bounds__(256) void flash_kernel(
    const unsigned short* __restrict__ qm, const unsigned short* __restrict__ km,
    const unsigned short* __restrict__ vm, unsigned short* __restrict__ om) {
    const int b = blockIdx.z, h = blockIdx.y, q0 = blockIdx.x << 6;
    const int tid = threadIdx.x, w = tid >> 6, lane = tid & 63, quad = lane >> 4, lr = lane & 15;
    __shared__ alignas(16) unsigned short Pl[4][16][72];  // per-wave P tile, +8 pad
    __shared__ alignas(16) unsigned short Vt[64][72];     // V^T [dh][key], +8 pad
    const size_t bS = (size_t)b * Sc;
    const int hoff = h << 6;

    s8v aq0, aq1;   // Q fragments, resident whole kernel (A: m=lane&15, k=quad*8+j)
    {
        const unsigned short* qr = qm + (bS + q0 + w * 16 + lr) * (size_t)Dc + hoff;
        aq0 = *(const s8v*)(qr + quad * 8);
        aq1 = *(const s8v*)(qr + 32 + quad * 8);
    }
    f4v accO[4];
#pragma unroll
    for (int i = 0; i < 4; i++) accO[i] = 0.f;
    float m_i[4] = {-3e38f, -3e38f, -3e38f, -3e38f};
    float l_i[4] = {0.f, 0.f, 0.f, 0.f};

    const int vkey = tid >> 2, vc = tid & 3;

    for (int kv0 = 0; kv0 < Sc; kv0 += 64) {
        // prefetch V chunk to regs
        const unsigned short* vp = vm + (bS + kv0 + vkey) * (size_t)Dc + hoff + vc * 16;
        s8v v0 = *(const s8v*)vp;
        s8v v1 = *(const s8v*)(vp + 8);
        __syncthreads();                 // prev iter's Pl/Vt reads complete
#pragma unroll
        for (int e = 0; e < 8; e++) {
            Vt[vc * 16 + e][vkey] = (unsigned short)v0[e];
            Vt[vc * 16 + 8 + e][vkey] = (unsigned short)v1[e];
        }
        // S = Q K^T * 1/sqrt(64); B-frags straight from global K rows (contig in dh)
        f4v sc4[4];
#pragma unroll
        for (int j = 0; j < 4; j++) {
            const unsigned short* kr = km + (bS + kv0 + j * 16 + lr) * (size_t)Dc + hoff;
            s8v b0 = *(const s8v*)(kr + quad * 8);
            s8v b1 = *(const s8v*)(kr + 32 + quad * 8);
            f4v c = 0.f;
            c = __builtin_amdgcn_mfma_f32_16x16x32_bf16(aq0, b0, c, 0, 0, 0);
            c = __builtin_amdgcn_mfma_f32_16x16x32_bf16(aq1, b1, c, 0, 0, 0);
            sc4[j] = c * 0.125f;
        }
        // online softmax; row = quad*4+rr, 16 lanes of a quad share rows
        float alpha[4], pmat[4][4];
#pragma unroll
        for (int rr = 0; rr < 4; rr++) {
            float lm = fmaxf(fmaxf(sc4[0][rr], sc4[1][rr]), fmaxf(sc4[2][rr], sc4[3][rr]));
#pragma unroll
            for (int off = 1; off < 16; off <<= 1) lm = fmaxf(lm, __shfl_xor(lm, off));
            float mn = fmaxf(m_i[rr], lm);
            alpha[rr] = __expf(m_i[rr] - mn);
            m_i[rr] = mn;
            float ls = 0.f;
#pragma unroll
            for (int j = 0; j < 4; j++) {
                float p = __expf(sc4[j][rr] - mn);
                pmat[j][rr] = p;
                ls += p;
            }
#pragma unroll
            for (int off = 1; off < 16; off <<= 1) ls += __shfl_xor(ls, off);
            l_i[rr] = l_i[rr] * alpha[rr] + ls;
        }
#pragma unroll
        for (int jd = 0; jd < 4; jd++)
#pragma unroll
            for (int rr = 0; rr < 4; rr++) accO[jd][rr] *= alpha[rr];
        // P: C-layout -> LDS -> A-layout roundtrip
#pragma unroll
        for (int j = 0; j < 4; j++)
#pragma unroll
            for (int rr = 0; rr < 4; rr++)
                Pl[w][quad * 4 + rr][j * 16 + lr] = f2bf(pmat[j][rr]);
        __syncthreads();                 // Vt staged (all waves) + P written
        s8v ap0 = *(const s8v*)&Pl[w][lr][quad * 8];
        s8v ap1 = *(const s8v*)&Pl[w][lr][32 + quad * 8];
#pragma unroll
        for (int jd = 0; jd < 4; jd++) {
            s8v b0 = *(const s8v*)&Vt[jd * 16 + lr][quad * 8];
            s8v b1 = *(const s8v*)&Vt[jd * 16 + lr][32 + quad * 8];
            accO[jd] = __builtin_amdgcn_mfma_f32_16x16x32_bf16(ap0, b0, accO[jd], 0, 0, 0);
            accO[jd] = __builtin_amdgcn_mfma_f32_16x16x32_bf16(ap1, b1, accO[jd], 0, 0, 0);
        }
    }
#pragma unroll
    for (int jd = 0; jd < 4; jd++)
#pragma unroll
        for (int rr = 0; rr < 4; rr++)
            om[(bS + q0 + w * 16 + quad * 4 + rr) * (size_t)Dc + hoff + jd * 16 + lr] =
                f2bf(accO[jd][rr] / l_i[rr]);
}

extern "C" void kernel_launch(void* const* d_in, const int* in_sizes, int n_in,
                              void* d_out, int out_size, void* d_ws, size_t ws_size,
                              hipStream_t stream) {
    const float* x  = (const float*)d_in[0];
    const int* idx  = (const int*)d_in[1];
    const float* Wq = (const float*)d_in[2];  const float* bq  = (const float*)d_in[3];
    const float* Wk = (const float*)d_in[4];  const float* bk  = (const float*)d_in[5];
    const float* Wv = (const float*)d_in[6];  const float* bv  = (const float*)d_in[7];
    const float* Wo = (const float*)d_in[8];  const float* bo  = (const float*)d_in[9];
    const float* s1 = (const float*)d_in[10]; const float* b1n = (const float*)d_in[11];
    const float* s2 = (const float*)d_in[12]; const float* b2n = (const float*)d_in[13];
    const float* W1 = (const float*)d_in[14]; const float* bf1 = (const float*)d_in[15];
    const float* W2 = (const float*)d_in[16]; const float* bf2 = (const float*)d_in[17];

    // workspace layout (bf16 elements unless noted); total ~416 MB
    const size_t eDD  = (size_t)Lc * Dc * Dc;   // 2^23
    const size_t eDF  = (size_t)Lc * Dc * Fc;   // 2^25
    const size_t eBSD = (size_t)Bc * Sc * Dc;   // 2^24
    unsigned short* Wtq = (unsigned short*)d_ws;
    unsigned short* Wtk = Wtq + eDD;
    unsigned short* Wtv = Wtk + eDD;
    unsigned short* Wto = Wtv + eDD;
    unsigned short* Wt1 = Wto + eDD;            // eDF
    unsigned short* Wt2 = Wt1 + eDF;            // eDF
    unsigned short* hb  = Wt2 + eDF;            // eBSD (h1 and h2)
    unsigned short* qb  = hb + eBSD;
    unsigned short* kb  = qb + eBSD;
    unsigned short* vb  = kb + eBSD;
    unsigned short* ab  = vb + eBSD;            // attn output
    float* x2           = (float*)(ab + eBSD);  // eBSD floats
    unsigned short* fb  = qb;                   // FFN hidden reuses q..attn (4*eBSD == B*S*F)

    dim3 blk(256);
    // 1) weight transpose+cast
    transpose_cast<<<dim3(Dc / 32, Dc / 32, Lc), blk, 0, stream>>>(Wq, Wtq, Dc, Dc);
    transpose_cast<<<dim3(Dc / 32, Dc / 32, Lc), blk, 0, stream>>>(Wk, Wtk, Dc, Dc);
    transpose_cast<<<dim3(Dc / 32, Dc / 32, Lc), blk, 0, stream>>>(Wv, Wtv, Dc, Dc);
    transpose_cast<<<dim3(Dc / 32, Dc / 32, Lc), blk, 0, stream>>>(Wo, Wto, Dc, Dc);
    transpose_cast<<<dim3(Fc / 32, Dc / 32, Lc), blk, 0, stream>>>(W1, Wt1, Dc, Fc);
    transpose_cast<<<dim3(Dc / 32, Fc / 32, Lc), blk, 0, stream>>>(W2, Wt2, Fc, Dc);
    // 2) LN1
    ln_kernel<<<Bc * Sc, blk, 0, stream>>>(x, s1, b1n, idx, hb);
    // 3) QKV projections
    gemm_kernel<0><<<dim3(Dc / 128, Sc / 128, Bc), blk, 0, stream>>>(hb, Wtq, bq, idx, nullptr, qb, Sc, Dc, Dc);
    gemm_kernel<0><<<dim3(Dc / 128, Sc / 128, Bc), blk, 0, stream>>>(hb, Wtk, bk, idx, nullptr, kb, Sc, Dc, Dc);
    gemm_kernel<0><<<dim3(Dc / 128, Sc / 128, Bc), blk, 0, stream>>>(hb, Wtv, bv, idx, nullptr, vb, Sc, Dc, Dc);
    // 4) attention
    flash_kernel<<<dim3(Sc / 64, Hc, Bc), blk, 0, stream>>>(qb, kb, vb, ab);
    // 5) output projection + residual -> x2 (fp32)
    gemm_kernel<2><<<dim3(Dc / 128, Sc / 128, Bc), blk, 0, stream>>>(ab, Wto, bo, idx, x, x2, Sc, Dc, Dc);
    // 6) LN2
    ln_kernel<<<Bc * Sc, blk, 0, stream>>>(x2, s2, b2n, idx, hb);
    // 7) FFN up + gelu
    gemm_kernel<1><<<dim3(Fc / 128, Sc / 128, Bc), blk, 0, stream>>>(hb, Wt1, bf1, idx, nullptr, fb, Sc, Fc, Dc);
    // 8) FFN down + residual -> d_out (fp32)
    gemm_kernel<2><<<dim3(Dc / 128, Sc / 128, Bc), blk, 0, stream>>>(fb, Wt2, bf2, idx, x2, (float*)d_out, Sc, Dc, Fc);
}